// Round 23
// baseline (96.267 us; speedup 1.0000x reference)
//
#include <hip/hip_runtime.h>
#include <hip/hip_bf16.h>
#include <cstdint>

#define B 32
#define L 512
#define T 2048
#define M 80
#define KDIM 160

#define NEG_INF (-1e30f)
#define LOG_2PI 1.8378770664093453f

typedef uint32_t u32;
typedef unsigned short u16;
typedef u16 u16x8 __attribute__((ext_vector_type(8)));
typedef short bf16x8 __attribute__((ext_vector_type(8)));
typedef float f32x4 __attribute__((ext_vector_type(4)));
typedef u32 u32x2 __attribute__((ext_vector_type(2)));

__device__ __forceinline__ int get_len(const int* __restrict__ p, int b) {
  return (p[1] == 0) ? p[2 * b] : p[b];
}

__device__ __forceinline__ u16 f2bf(float f) {
  __hip_bfloat16 h = __float2bfloat16(f);
  return *(u16*)&h;
}

// ---------------- prep_all: Wfrag + bias (blocks 0-63), Xfrag (blocks 64+) -----
__global__ __launch_bounds__(256) void prep_all(const float* __restrict__ mu_sigma,
                                                const float* __restrict__ melspec,
                                                u16* __restrict__ Wfrag,
                                                u16* __restrict__ Xfrag,
                                                float* __restrict__ biasv) {
  int bid = blockIdx.x;
  int tid = threadIdx.x;
  if (bid < 64) {
    int gid = bid * 256 + tid;  // b*L + l
    int b = gid >> 9;
    int l = gid & (L - 1);
    const float* row = mu_sigma + (size_t)gid * (2 * M);
    float acc_a = 0.f, acc_ls = 0.f;
#pragma unroll 2
    for (int g = 0; g < 10; ++g) {
      u16x8 wsq, wli;
#pragma unroll
      for (int j = 0; j < 8; ++j) {
        float mu = row[g * 8 + j];
        float ls = row[M + g * 8 + j];
        float iv = expf(-2.f * ls);
        acc_a += mu * mu * iv;
        acc_ls += ls;
        wsq[j] = f2bf(-0.5f * iv);
        wli[j] = f2bf(mu * iv);
      }
      *(u16x8*)(Wfrag + ((size_t)(b * 20 + g) * L + l) * 8) = wsq;
      *(u16x8*)(Wfrag + ((size_t)(b * 20 + 10 + g) * L + l) * 8) = wli;
    }
    biasv[gid] = -0.5f * acc_a - (0.5f * (float)M * LOG_2PI + 0.5f * acc_ls);
  } else {
    int gid = (bid - 64) * 256 + tid;  // (b*10 + mg)*T + t
    int t = gid & (T - 1);
    int rest = gid >> 11;
    int mg = rest % 10;
    int b = rest / 10;
    u16x8 sq, li;
#pragma unroll
    for (int j = 0; j < 8; ++j) {
      float xv = melspec[((size_t)b * M + mg * 8 + j) * T + t];
      sq[j] = f2bf(xv * xv);
      li[j] = f2bf(xv);
    }
    *(u16x8*)(Xfrag + ((size_t)(b * 20 + mg) * T + t) * 8) = sq;
    *(u16x8*)(Xfrag + ((size_t)(b * 20 + 10 + mg) * T + t) * 8) = li;
  }
}

// ---------------- gemm (MFMA): 128t x 128l block, wave = 64x64 -----------------
__global__ __launch_bounds__(256) void gemm_logp(const u16* __restrict__ Xfrag,
                                                 const u16* __restrict__ Wfrag,
                                                 const float* __restrict__ biasv,
                                                 const int* __restrict__ mel_len,
                                                 const int* __restrict__ text_len,
                                                 u16* __restrict__ logpT,
                                                 int t_begin, int tc) {
  int b = blockIdx.z;
  int t0 = t_begin + blockIdx.x * 128;
  int l0 = blockIdx.y * 128;
  if (t0 >= get_len(mel_len, b)) return;
  if (l0 >= get_len(text_len, b)) return;

  int tid = threadIdx.x;
  int wave = tid >> 6, lane = tid & 63;
  int wt = wave >> 1, wl = wave & 1;
  int mbase = t0 + wt * 64;
  int nbase = l0 + wl * 64;
  int l16 = lane & 15, khalf = lane >> 4;

  const bf16x8* Xp = (const bf16x8*)Xfrag;
  const bf16x8* Wp = (const bf16x8*)Wfrag;

  f32x4 acc[4][4];
#pragma unroll
  for (int i = 0; i < 4; ++i)
#pragma unroll
    for (int j = 0; j < 4; ++j) acc[i][j] = (f32x4){0.f, 0.f, 0.f, 0.f};

#pragma unroll
  for (int ks = 0; ks < 5; ++ks) {
    int kc = ks * 4 + khalf;
    size_t xb = (size_t)(b * 20 + kc) * T;
    size_t wb = (size_t)(b * 20 + kc) * L;
    bf16x8 a0 = Xp[xb + mbase + l16];
    bf16x8 a1 = Xp[xb + mbase + 16 + l16];
    bf16x8 a2 = Xp[xb + mbase + 32 + l16];
    bf16x8 a3 = Xp[xb + mbase + 48 + l16];
    bf16x8 b0 = Wp[wb + nbase + l16];
    bf16x8 b1 = Wp[wb + nbase + 16 + l16];
    bf16x8 b2 = Wp[wb + nbase + 32 + l16];
    bf16x8 b3 = Wp[wb + nbase + 48 + l16];
    acc[0][0] = __builtin_amdgcn_mfma_f32_16x16x32_bf16(a0, b0, acc[0][0], 0, 0, 0);
    acc[0][1] = __builtin_amdgcn_mfma_f32_16x16x32_bf16(a0, b1, acc[0][1], 0, 0, 0);
    acc[0][2] = __builtin_amdgcn_mfma_f32_16x16x32_bf16(a0, b2, acc[0][2], 0, 0, 0);
    acc[0][3] = __builtin_amdgcn_mfma_f32_16x16x32_bf16(a0, b3, acc[0][3], 0, 0, 0);
    acc[1][0] = __builtin_amdgcn_mfma_f32_16x16x32_bf16(a1, b0, acc[1][0], 0, 0, 0);
    acc[1][1] = __builtin_amdgcn_mfma_f32_16x16x32_bf16(a1, b1, acc[1][1], 0, 0, 0);
    acc[1][2] = __builtin_amdgcn_mfma_f32_16x16x32_bf16(a1, b2, acc[1][2], 0, 0, 0);
    acc[1][3] = __builtin_amdgcn_mfma_f32_16x16x32_bf16(a1, b3, acc[1][3], 0, 0, 0);
    acc[2][0] = __builtin_amdgcn_mfma_f32_16x16x32_bf16(a2, b0, acc[2][0], 0, 0, 0);
    acc[2][1] = __builtin_amdgcn_mfma_f32_16x16x32_bf16(a2, b1, acc[2][1], 0, 0, 0);
    acc[2][2] = __builtin_amdgcn_mfma_f32_16x16x32_bf16(a2, b2, acc[2][2], 0, 0, 0);
    acc[2][3] = __builtin_amdgcn_mfma_f32_16x16x32_bf16(a2, b3, acc[2][3], 0, 0, 0);
    acc[3][0] = __builtin_amdgcn_mfma_f32_16x16x32_bf16(a3, b0, acc[3][0], 0, 0, 0);
    acc[3][1] = __builtin_amdgcn_mfma_f32_16x16x32_bf16(a3, b1, acc[3][1], 0, 0, 0);
    acc[3][2] = __builtin_amdgcn_mfma_f32_16x16x32_bf16(a3, b2, acc[3][2], 0, 0, 0);
    acc[3][3] = __builtin_amdgcn_mfma_f32_16x16x32_bf16(a3, b3, acc[3][3], 0, 0, 0);
  }

  // epilogue: C/D map col = lane&15, row = khalf*4 + r  [verified m89/m91]
  int rbase = khalf * 4;
#pragma unroll
  for (int j = 0; j < 4; ++j) {
    int colL = nbase + j * 16 + l16;
    float bias = biasv[b * L + colL];
#pragma unroll
    for (int i = 0; i < 4; ++i) {
#pragma unroll
      for (int r = 0; r < 4; ++r) {
        int t = mbase + i * 16 + rbase + r;
        logpT[((size_t)b * tc + (t - t_begin)) * L + colL] = f2bf(acc[i][j][r] + bias);
      }
    }
  }
}

// ---------------- scan machinery ----------------
#define SR_F 64   // fused: 2-slot ring, 64 rows/phase (16/wave), single barrier
#define SR_C 64   // chunked fallback

#define VMW(n)                                             \
  do {                                                     \
    asm volatile("s_waitcnt vmcnt(" #n ")" ::: "memory");  \
    __builtin_amdgcn_sched_barrier(0);                     \
  } while (0)
#define LGKMC(n)                                           \
  do {                                                     \
    asm volatile("s_waitcnt lgkmcnt(" #n ")" ::: "memory");\
    __builtin_amdgcn_sched_barrier(0);                     \
  } while (0)
#define BAR()                                              \
  do {                                                     \
    asm volatile("" ::: "memory");                         \
    __builtin_amdgcn_s_barrier();                          \
    asm volatile("" ::: "memory");                         \
  } while (0)
#define RD64(dst, addr, imm) \
  asm volatile("ds_read_b64 %0, %1 offset:%c2" : "=v"(dst) : "v"(addr), "i"(imm))
#define RD4(P, base_)                 \
  do {                                \
    RD64(P##0, ringA, (base_));       \
    RD64(P##1, ringA, (base_) + 1024);\
    RD64(P##2, ringA, (base_) + 2048);\
    RD64(P##3, ringA, (base_) + 3072);\
  } while (0)
#define S4(P)                                     \
  do { stepv(P##0); stepv(P##1); stepv(P##2); stepv(P##3); } while (0)

// 16-group phase (64 rows): 3 read-buffers, steady lgkmcnt(8); halo applied
// after the first counted wait.
#define PHASE16()                                               \
  do {                                                          \
    u32x2 qA0, qA1, qA2, qA3, qB0, qB1, qB2, qB3,               \
          qC0, qC1, qC2, qC3;                                   \
    RD4(qA, 0); RD4(qB, 4096); RD4(qC, 8192);                   \
    LGKMC(8);                                                   \
    if (do_halo) {                                              \
      c0 = __uint_as_float(h01.x); c1 = __uint_as_float(h01.y); \
      c2 = __uint_as_float(h23.x); c3 = __uint_as_float(h23.y); \
    }                                                           \
    S4(qA); RD4(qA, 12288);                                     \
    LGKMC(8); S4(qB); RD4(qB, 16384);                           \
    LGKMC(8); S4(qC); RD4(qC, 20480);                           \
    LGKMC(8); S4(qA); RD4(qA, 24576);                           \
    LGKMC(8); S4(qB); RD4(qB, 28672);                           \
    LGKMC(8); S4(qC); RD4(qC, 32768);                           \
    LGKMC(8); S4(qA); RD4(qA, 36864);                           \
    LGKMC(8); S4(qB); RD4(qB, 40960);                           \
    LGKMC(8); S4(qC); RD4(qC, 45056);                           \
    LGKMC(8); S4(qA); RD4(qA, 49152);                           \
    LGKMC(8); S4(qB); RD4(qB, 53248);                           \
    LGKMC(8); S4(qC); RD4(qC, 57344);                           \
    LGKMC(8); S4(qA); RD4(qA, 61440);                           \
    LGKMC(8); S4(qB);                                           \
    LGKMC(4); S4(qC);                                           \
    LGKMC(0); S4(qA);                                           \
  } while (0)

__device__ __forceinline__ float dpp_shr1_neginf(float x) {  // dst[i]=src[i-1]
  int r = __builtin_amdgcn_update_dpp(__float_as_int(NEG_INF), __float_as_int(x),
                                      0x138, 0xf, 0xf, false);  // wave_shr:1
  return __int_as_float(r);
}
__device__ __forceinline__ float dpp_shl1_neginf(float x) {  // dst[i]=src[i+1]
  int r = __builtin_amdgcn_update_dpp(__float_as_int(NEG_INF), __float_as_int(x),
                                      0x130, 0xf, 0xf, false);  // wave_shl:1
  return __int_as_float(r);
}

// ---------------- fused fwd/bwd scan: 64 blocks, 2-slot single-barrier ---------
// Single barrier/phase with a 2-slot ring is safe: stage(k+1) is issued AFTER
// the phase-k barrier; slot (k+1)&1 was last read in phase k-1, which every
// wave completed before arriving at that barrier, and DMA writes cannot
// precede their issue. VMW(16) after issuing stage(k+1) retires stage(k)
// (32 outstanding -> 16).
__global__ __launch_bounds__(256, 1) void scan_fused(const u16* __restrict__ logpT,
                                                     const int* __restrict__ mel_len,
                                                     const int* __restrict__ text_len,
                                                     float* __restrict__ cwsF,
                                                     float* __restrict__ cwsB) {
  __shared__ u16 ring[2][SR_F][L];    // 128 KB
  __shared__ float smem[2][L];        // 4 KB halo exchange
  int tid = threadIdx.x;
  int wave = tid >> 6;
  int lane = tid & 63;
  bool bwdk = (blockIdx.x >= B);
  int b = bwdk ? (int)blockIdx.x - B : (int)blockIdx.x;
  int ml = get_len(mel_len, b);
  int tl = get_len(text_len, b);
  int tmid = ml >> 1;
  const u16* base0 = logpT + (size_t)b * T * L;

  if (!bwdk) {
    // ================= forward: alpha over t in [1, tmid) =================
    float* cws = cwsF + b * L;
    int col_lane = 128 * wave - 128 + 4 * lane;
    int cl = (col_lane < 0) ? 0 : col_lane;
    bool halo_lane = (wave > 0) && (lane < 32);
    bool owner = (lane >= 32);

    float c0 = NEG_INF, c1 = NEG_INF, c2 = NEG_INF, c3 = NEG_INF;
    if (wave == 0 && lane == 32) c0 = __uint_as_float((u32)base0[0] << 16);
    int nrows = tmid - 1;
    int tlast = tmid - 1;

    auto stepv = [&](u32x2 v) {
      float p = dpp_shr1_neginf(c3);
      float f0 = __uint_as_float(v.x << 16);
      float f1 = __uint_as_float(v.x & 0xFFFF0000u);
      float f2 = __uint_as_float(v.y << 16);
      float f3 = __uint_as_float(v.y & 0xFFFF0000u);
      c3 = fmaxf(c3, c2) + f3;
      c2 = fmaxf(c2, c1) + f2;
      c1 = fmaxf(c1, c0) + f1;
      c0 = fmaxf(c0, p) + f0;
    };

    if (nrows > 0) {
      int np = (nrows + SR_F - 1) / SR_F;
      auto stage = [&](int ph) -> bool {
        if (ph >= np) return false;
        int pr = 1 + ph * SR_F + 16 * wave;
        u16* d0 = &ring[ph & 1][16 * wave][0];
#pragma unroll
        for (int j = 0; j < 16; ++j) {
          int t = pr + j;
          t = (t > tlast) ? tlast : t;
          const u16* s = base0 + (size_t)t * L + lane * 8;
          __builtin_amdgcn_global_load_lds(
              (const __attribute__((address_space(1))) void*)s,
              (__attribute__((address_space(3))) void*)(d0 + (size_t)j * L + lane * 8),
              16, 0, 0);
        }
        return true;
      };
      stage(0);
      for (int k = 0; k < np; ++k) {
        BAR();  // all waves finished phase k-1; slot (k+1)&1 free
        u32x2 h01, h23;
        bool do_halo = (k > 0) && halo_lane;
        if (do_halo) {
          u32 ha = (u32)(uintptr_t)(__attribute__((address_space(3)))
                                    float*)(&smem[(k - 1) & 1][col_lane]);
          RD64(h01, ha, 0);
          RD64(h23, ha, 8);
        }
        bool nx = stage(k + 1);
        if (nx) VMW(16); else VMW(0);  // stage(k) landed
        int rem = nrows - k * SR_F;
        if (rem > SR_F) rem = SR_F;
        u32 ringA = (u32)(uintptr_t)(__attribute__((address_space(3)))
                                     u16*)(&ring[k & 1][0][0]) +
                    2u * (u32)cl;
        if (rem == SR_F) {
          PHASE16();
        } else {
          LGKMC(0);
          if (do_halo) {
            c0 = __uint_as_float(h01.x); c1 = __uint_as_float(h01.y);
            c2 = __uint_as_float(h23.x); c3 = __uint_as_float(h23.y);
          }
          const char* rp = (const char*)(&ring[k & 1][0][0]) + 2 * cl;
          for (int r = 0; r < rem; ++r) {
            u32x2 v = *(const u32x2*)(rp + (size_t)r * (L * 2));
            stepv(v);
          }
        }
        if (owner) *(float4*)&smem[k & 1][col_lane] = make_float4(c0, c1, c2, c3);
        LGKMC(0);
      }
    }
    if (owner) *(float4*)(cws + col_lane) = make_float4(c0, c1, c2, c3);
  } else {
    // ============ backward: beta over t = ml-2 .. tmid, mirrored ============
    float* cws = cwsB + b * L;
    int col_lane = 128 * wave + 4 * lane;        // up to 639 for wave3 halo
    int cl = (col_lane > 508) ? 508 : col_lane;  // clamped for loads
    bool halo_lane = (lane >= 32) && (wave < 3);
    bool owner = (lane < 32);

    float c0 = NEG_INF, c1 = NEG_INF, c2 = NEG_INF, c3 = NEG_INF;
    {
      int li = tl - 1;
      int d = li - col_lane;
      if (d >= 0 && d < 4) {
        float v = __uint_as_float((u32)base0[(size_t)(ml - 1) * L + li] << 16);
        if (d == 0) c0 = v; else if (d == 1) c1 = v;
        else if (d == 2) c2 = v; else c3 = v;
      }
    }
    int nrows = ml - 1 - tmid;
    int tb0 = ml - 2;

    auto stepv = [&](u32x2 v) {
      float p = dpp_shl1_neginf(c0);
      float f0 = __uint_as_float(v.x << 16);
      float f1 = __uint_as_float(v.x & 0xFFFF0000u);
      float f2 = __uint_as_float(v.y << 16);
      float f3 = __uint_as_float(v.y & 0xFFFF0000u);
      c0 = fmaxf(c0, c1) + f0;
      c1 = fmaxf(c1, c2) + f1;
      c2 = fmaxf(c2, c3) + f2;
      c3 = fmaxf(c3, p) + f3;
    };

    if (nrows > 0) {
      int np = (nrows + SR_F - 1) / SR_F;
      auto stage = [&](int ph) -> bool {
        if (ph >= np) return false;
        int pr = tb0 - ph * SR_F - 16 * wave;
        u16* d0 = &ring[ph & 1][16 * wave][0];
#pragma unroll
        for (int j = 0; j < 16; ++j) {
          int t = pr - j;
          t = (t < 0) ? 0 : t;
          const u16* s = base0 + (size_t)t * L + lane * 8;
          __builtin_amdgcn_global_load_lds(
              (const __attribute__((address_space(1))) void*)s,
              (__attribute__((address_space(3))) void*)(d0 + (size_t)j * L + lane * 8),
              16, 0, 0);
        }
        return true;
      };
      stage(0);
      for (int k = 0; k < np; ++k) {
        BAR();
        u32x2 h01, h23;
        bool do_halo = (k > 0) && halo_lane;
        if (do_halo) {
          u32 ha = (u32)(uintptr_t)(__attribute__((address_space(3)))
                                    float*)(&smem[(k - 1) & 1][col_lane]);
          RD64(h01, ha, 0);
          RD64(h23, ha, 8);
        }
        bool nx = stage(k + 1);
        if (nx) VMW(16); else VMW(0);
        int rem = nrows - k * SR_F;
        if (rem > SR_F) rem = SR_F;
        u32 ringA = (u32)(uintptr_t)(__attribute__((address_space(3)))
                                     u16*)(&ring[k & 1][0][0]) +
                    2u * (u32)cl;
        if (rem == SR_F) {
          PHASE16();
        } else {
          LGKMC(0);
          if (do_halo) {
            c0 = __uint_as_float(h01.x); c1 = __uint_as_float(h01.y);
            c2 = __uint_as_float(h23.x); c3 = __uint_as_float(h23.y);
          }
          const char* rp = (const char*)(&ring[k & 1][0][0]) + 2 * cl;
          for (int r = 0; r < rem; ++r) {
            u32x2 v = *(const u32x2*)(rp + (size_t)r * (L * 2));
            stepv(v);
          }
        }
        if (owner) *(float4*)&smem[k & 1][col_lane] = make_float4(c0, c1, c2, c3);
        LGKMC(0);
      }
    }
    if (owner) *(float4*)(cws + col_lane) = make_float4(c0, c1, c2, c3);
  }
}

// ---------------- combine + reduce (one block): out = -mean_b la[b] ------------
__global__ __launch_bounds__(256) void combine_reduce(const float* __restrict__ cwsF,
                                                      const float* __restrict__ cwsB,
                                                      float* __restrict__ out) {
  __shared__ float la_s[32];
  int tid = threadIdx.x;
  int b = tid >> 3;
  int j0 = (tid & 7) * 64;
  const float* f = cwsF + b * L;
  const float* bbp = cwsB + b * L;
  float m = NEG_INF;
  for (int j = 0; j < 64; ++j) {
    int l = j0 + j;
    float b1 = (l + 1 < L) ? bbp[l + 1] : NEG_INF;
    m = fmaxf(m, f[l] + fmaxf(bbp[l], b1));
  }
  m = fmaxf(m, __shfl_xor(m, 1));
  m = fmaxf(m, __shfl_xor(m, 2));
  m = fmaxf(m, __shfl_xor(m, 4));
  if ((tid & 7) == 0) la_s[b] = m;
  __syncthreads();
  if (tid < 64) {
    float v = (tid < 32) ? la_s[tid] : 0.f;
#pragma unroll
    for (int s = 32; s > 0; s >>= 1) v += __shfl_down(v, s);
    if (tid == 0) out[0] = -v * (1.0f / (float)B);
  }
}

// ---------------- fallback chunked forward scan (R19/R20, proven) --------------
__global__ __launch_bounds__(256, 1) void scan_kernel(const u16* __restrict__ logpT,
                                                      const int* __restrict__ mel_len,
                                                      const int* __restrict__ text_len,
                                                      float* __restrict__ carry_ws,
                                                      float* __restrict__ la_ws,
                                                      int t_begin, int tc) {
  __shared__ u16 ring[2][SR_C][L];
  __shared__ float smem[2][L];
  int tid = threadIdx.x;
  int wave = tid >> 6;
  int lane = tid & 63;
  int b = blockIdx.x;
  int ml = get_len(mel_len, b);
  int tl = get_len(text_len, b);
  const u16* base0 = logpT + (size_t)b * tc * L;
  float* cws = carry_ws + b * L;
  int col_lane = 128 * wave - 128 + 4 * lane;
  int cl = (col_lane < 0) ? 0 : col_lane;
  bool halo_lane = (wave > 0) && (lane < 32);
  bool owner = (lane >= 32);

  float c0 = NEG_INF, c1 = NEG_INF, c2 = NEG_INF, c3 = NEG_INF;
  int tstart;
  if (t_begin == 0) {
    if (wave == 0 && lane == 32) c0 = __uint_as_float((u32)base0[0] << 16);
    tstart = 1;
  } else {
    float4 v = *(const float4*)(cws + cl);
    c0 = v.x; c1 = v.y; c2 = v.z; c3 = v.w;
    if (col_lane < 0) { c0 = NEG_INF; c1 = NEG_INF; c2 = NEG_INF; c3 = NEG_INF; }
    tstart = t_begin;
  }

  int tstop = min(t_begin + tc, ml);
  int nrows = tstop - tstart;

  auto stepv = [&](u32x2 v) {
    float p = dpp_shr1_neginf(c3);
    float f0 = __uint_as_float(v.x << 16);
    float f1 = __uint_as_float(v.x & 0xFFFF0000u);
    float f2 = __uint_as_float(v.y << 16);
    float f3 = __uint_as_float(v.y & 0xFFFF0000u);
    c3 = fmaxf(c3, c2) + f3;
    c2 = fmaxf(c2, c1) + f2;
    c1 = fmaxf(c1, c0) + f1;
    c0 = fmaxf(c0, p) + f0;
  };

  if (nrows > 0) {
    int np = (nrows + SR_C - 1) / SR_C;
    int tlast = tstop - 1;
    auto stage = [&](int ph) -> bool {
      if (ph >= np) return false;
      int pr = tstart + ph * SR_C + 16 * wave;
      u16* d0 = &ring[ph & 1][16 * wave][0];
#pragma unroll
      for (int j = 0; j < 16; ++j) {
        int t = pr + j;
        t = (t > tlast) ? tlast : t;
        const u16* s = base0 + (size_t)(t - t_begin) * L + lane * 8;
        __builtin_amdgcn_global_load_lds(
            (const __attribute__((address_space(1))) void*)s,
            (__attribute__((address_space(3))) void*)(d0 + (size_t)j * L + lane * 8),
            16, 0, 0);
      }
      return true;
    };
    stage(0);
    for (int k = 0; k < np; ++k) {
      BAR();
      u32x2 h01, h23;
      bool do_halo = (k > 0) && halo_lane;
      if (do_halo) {
        u32 ha = (u32)(uintptr_t)(__attribute__((address_space(3)))
                                  float*)(&smem[(k - 1) & 1][col_lane]);
        RD64(h01, ha, 0);
        RD64(h23, ha, 8);
      }
      bool nx = stage(k + 1);
      if (nx) VMW(16); else VMW(0);
      int rem = nrows - k * SR_C;
      if (rem > SR_C) rem = SR_C;
      u32 ringA = (u32)(uintptr_t)(__attribute__((address_space(3)))
                                   u16*)(&ring[k & 1][0][0]) +
                  2u * (u32)cl;
      if (rem == SR_C) {
        PHASE16();
      } else {
        LGKMC(0);
        if (do_halo) {
          c0 = __uint_as_float(h01.x); c1 = __uint_as_float(h01.y);
          c2 = __uint_as_float(h23.x); c3 = __uint_as_float(h23.y);
        }
        const char* rp = (const char*)(&ring[k & 1][0][0]) + 2 * cl;
        for (int r = 0; r < rem; ++r) {
          u32x2 v = *(const u32x2*)(rp + (size_t)r * (L * 2));
          stepv(v);
        }
      }
      if (owner) *(float4*)&smem[k & 1][col_lane] = make_float4(c0, c1, c2, c3);
      LGKMC(0);
    }
  }

  if (owner) *(float4*)(cws + col_lane) = make_float4(c0, c1, c2, c3);

  if (t_begin + tc >= T) {
    int li = tl - 1;
    int w_own = li >> 7;
    if (wave == w_own) {
      int sub = li & 3;
      float v = (sub == 0) ? c0 : (sub == 1) ? c1 : (sub == 2) ? c2 : c3;
      float lav = __shfl(v, 32 + ((li & 127) >> 2));
      if (lane == 0) la_ws[b] = lav;
    }
  }
}

__global__ __launch_bounds__(64) void reduce_kernel(const float* __restrict__ la_ws,
                                                    float* __restrict__ out) {
  int lane = threadIdx.x;
  float v = (lane < B) ? la_ws[lane] : 0.f;
#pragma unroll
  for (int s = 32; s > 0; s >>= 1) v += __shfl_down(v, s);
  if (lane == 0) out[0] = -v * (1.0f / (float)B);
}

extern "C" void kernel_launch(void* const* d_in, const int* in_sizes, int n_in,
                              void* d_out, int out_size, void* d_ws, size_t ws_size,
                              hipStream_t stream) {
  const float* mu_sigma = (const float*)d_in[0];
  const float* melspec  = (const float*)d_in[1];
  const int*   text_len = (const int*)d_in[2];
  const int*   mel_len  = (const int*)d_in[3];
  float* out = (float*)d_out;

  char* ws = (char*)d_ws;
  size_t off = 0;
  u16* Wfrag = (u16*)(ws + off);         off += (size_t)B * KDIM * L * 2;      // 5.2 MB
  float* biasv = (float*)(ws + off);     off += (size_t)B * L * 4;
  float* cwsF = (float*)(ws + off);      off += (size_t)B * L * 4;
  float* cwsB = (float*)(ws + off);      off += (size_t)B * L * 4;
  float* la_ws = (float*)(ws + off);     off += 256;
  u16* Xfrag = (u16*)(ws + off);         off += (size_t)B * KDIM * T * 2;      // 21 MB
  u16* logpT = (u16*)(ws + off);
  size_t avail = (ws_size > off) ? (ws_size - off) : 0;
  size_t per_t = (size_t)B * L * 2;  // bytes per t-slice across all b (bf16)
  long long tcl = (long long)(avail / per_t);
  int Tc = (tcl > T) ? T : (int)tcl;
  Tc &= ~127;
  if (Tc < 128) return;  // insufficient workspace (not expected)

  prep_all<<<dim3(64 + (B * 10 * T) / 256), 256, 0, stream>>>(mu_sigma, melspec,
                                                              Wfrag, Xfrag, biasv);

  if (Tc == T) {
    // primary: single-chunk gemm + fused fwd/bwd scan on 64 CUs
    dim3 grid(T / 128, L / 128, B);
    gemm_logp<<<grid, 256, 0, stream>>>(Xfrag, Wfrag, biasv, mel_len, text_len,
                                        logpT, 0, T);
    scan_fused<<<dim3(2 * B), 256, 0, stream>>>(logpT, mel_len, text_len, cwsF, cwsB);
    combine_reduce<<<dim3(1), 256, 0, stream>>>(cwsF, cwsB, out);
  } else {
    // fallback: chunked forward-only (R19 path)
    for (int t_begin = 0; t_begin < T; t_begin += Tc) {
      int tc = (T - t_begin < Tc) ? (T - t_begin) : Tc;
      dim3 grid(tc / 128, L / 128, B);
      gemm_logp<<<grid, 256, 0, stream>>>(Xfrag, Wfrag, biasv, mel_len, text_len,
                                          logpT, t_begin, tc);
      scan_kernel<<<dim3(B), 256, 0, stream>>>(logpT, mel_len, text_len, cwsF,
                                               la_ws, t_begin, tc);
    }
    reduce_kernel<<<1, 64, 0, stream>>>(la_ws, out);
  }
}

// Round 24
// 93.378 us; speedup vs baseline: 1.0309x; 1.0309x over previous
//
#include <hip/hip_runtime.h>
#include <hip/hip_bf16.h>
#include <cstdint>

#define B 32
#define L 512
#define T 2048
#define M 80
#define KDIM 160

#define NEG_INF (-1e30f)
#define LOG_2PI 1.8378770664093453f

typedef uint32_t u32;
typedef unsigned short u16;
typedef u16 u16x8 __attribute__((ext_vector_type(8)));
typedef short bf16x8 __attribute__((ext_vector_type(8)));
typedef float f32x4 __attribute__((ext_vector_type(4)));
typedef u32 u32x2 __attribute__((ext_vector_type(2)));

__device__ __forceinline__ int get_len(const int* __restrict__ p, int b) {
  return (p[1] == 0) ? p[2 * b] : p[b];
}

__device__ __forceinline__ u16 f2bf(float f) {
  __hip_bfloat16 h = __float2bfloat16(f);
  return *(u16*)&h;
}

// ---------------- prep: Wfrag[b][kc][l][8] (bf16 B-fragments), bias[b][l] --------
__global__ __launch_bounds__(256) void prep_kernel(const float* __restrict__ mu_sigma,
                                                   u16* __restrict__ Wfrag,
                                                   float* __restrict__ biasv) {
  int gid = blockIdx.x * 256 + threadIdx.x;  // b*L + l
  if (gid >= B * L) return;
  int b = gid >> 9;
  int l = gid & (L - 1);
  const float* row = mu_sigma + (size_t)gid * (2 * M);
  float acc_a = 0.f, acc_ls = 0.f;
#pragma unroll 2
  for (int g = 0; g < 10; ++g) {
    u16x8 wsq, wli;
#pragma unroll
    for (int j = 0; j < 8; ++j) {
      float mu = row[g * 8 + j];
      float ls = row[M + g * 8 + j];
      float iv = expf(-2.f * ls);
      acc_a += mu * mu * iv;
      acc_ls += ls;
      wsq[j] = f2bf(-0.5f * iv);
      wli[j] = f2bf(mu * iv);
    }
    *(u16x8*)(Wfrag + ((size_t)(b * 20 + g) * L + l) * 8) = wsq;
    *(u16x8*)(Wfrag + ((size_t)(b * 20 + 10 + g) * L + l) * 8) = wli;
  }
  biasv[gid] = -0.5f * acc_a - (0.5f * (float)M * LOG_2PI + 0.5f * acc_ls);
}

// ---------------- xprep: Xfrag[b][kc][t][8] (bf16 A-fragments) ----------------
__global__ __launch_bounds__(256) void xprep_kernel(const float* __restrict__ melspec,
                                                    u16* __restrict__ Xfrag) {
  int gid = blockIdx.x * 256 + threadIdx.x;  // (b*10 + mg)*T + t
  int t = gid & (T - 1);
  int rest = gid >> 11;
  int mg = rest % 10;
  int b = rest / 10;
  u16x8 sq, li;
#pragma unroll
  for (int j = 0; j < 8; ++j) {
    float xv = melspec[((size_t)b * M + mg * 8 + j) * T + t];
    sq[j] = f2bf(xv * xv);
    li[j] = f2bf(xv);
  }
  *(u16x8*)(Xfrag + ((size_t)(b * 20 + mg) * T + t) * 8) = sq;
  *(u16x8*)(Xfrag + ((size_t)(b * 20 + 10 + mg) * T + t) * 8) = li;
}

// ---------------- gemm (MFMA): logpT[b][t][l] bf16 = bias + sum_k X*W ----------
__global__ __launch_bounds__(256) void gemm_logp(const u16* __restrict__ Xfrag,
                                                 const u16* __restrict__ Wfrag,
                                                 const float* __restrict__ biasv,
                                                 const int* __restrict__ mel_len,
                                                 const int* __restrict__ text_len,
                                                 u16* __restrict__ logpT,
                                                 int t_begin, int tc) {
  int b = blockIdx.z;
  int t0 = t_begin + blockIdx.x * 64;
  int l0 = blockIdx.y * 128;
  if (t0 >= get_len(mel_len, b)) return;
  if (l0 >= get_len(text_len, b)) return;

  int tid = threadIdx.x;
  int wave = tid >> 6, lane = tid & 63;
  int wt = wave >> 1, wl = wave & 1;
  int mbase = t0 + wt * 32;
  int nbase = l0 + wl * 64;
  int l16 = lane & 15, khalf = lane >> 4;

  const bf16x8* Xp = (const bf16x8*)Xfrag;
  const bf16x8* Wp = (const bf16x8*)Wfrag;

  f32x4 acc[2][4];
#pragma unroll
  for (int i = 0; i < 2; ++i)
#pragma unroll
    for (int j = 0; j < 4; ++j) acc[i][j] = (f32x4){0.f, 0.f, 0.f, 0.f};

#pragma unroll
  for (int ks = 0; ks < 5; ++ks) {
    int kc = ks * 4 + khalf;
    size_t xb = (size_t)(b * 20 + kc) * T;
    size_t wb = (size_t)(b * 20 + kc) * L;
    bf16x8 a0 = Xp[xb + mbase + l16];
    bf16x8 a1 = Xp[xb + mbase + 16 + l16];
    bf16x8 b0 = Wp[wb + nbase + l16];
    bf16x8 b1 = Wp[wb + nbase + 16 + l16];
    bf16x8 b2 = Wp[wb + nbase + 32 + l16];
    bf16x8 b3 = Wp[wb + nbase + 48 + l16];
    acc[0][0] = __builtin_amdgcn_mfma_f32_16x16x32_bf16(a0, b0, acc[0][0], 0, 0, 0);
    acc[0][1] = __builtin_amdgcn_mfma_f32_16x16x32_bf16(a0, b1, acc[0][1], 0, 0, 0);
    acc[0][2] = __builtin_amdgcn_mfma_f32_16x16x32_bf16(a0, b2, acc[0][2], 0, 0, 0);
    acc[0][3] = __builtin_amdgcn_mfma_f32_16x16x32_bf16(a0, b3, acc[0][3], 0, 0, 0);
    acc[1][0] = __builtin_amdgcn_mfma_f32_16x16x32_bf16(a1, b0, acc[1][0], 0, 0, 0);
    acc[1][1] = __builtin_amdgcn_mfma_f32_16x16x32_bf16(a1, b1, acc[1][1], 0, 0, 0);
    acc[1][2] = __builtin_amdgcn_mfma_f32_16x16x32_bf16(a1, b2, acc[1][2], 0, 0, 0);
    acc[1][3] = __builtin_amdgcn_mfma_f32_16x16x32_bf16(a1, b3, acc[1][3], 0, 0, 0);
  }

  int rbase = khalf * 4;
#pragma unroll
  for (int j = 0; j < 4; ++j) {
    int colL = nbase + j * 16 + l16;
    float bias = biasv[b * L + colL];
#pragma unroll
    for (int i = 0; i < 2; ++i) {
#pragma unroll
      for (int r = 0; r < 4; ++r) {
        int t = mbase + i * 16 + rbase + r;
        logpT[((size_t)b * tc + (t - t_begin)) * L + colL] = f2bf(acc[i][j][r] + bias);
      }
    }
  }
}

// ---------------- scan machinery (shared macros) ----------------
#define SROWS 64

#define VMW(n)                                             \
  do {                                                     \
    asm volatile("s_waitcnt vmcnt(" #n ")" ::: "memory");  \
    __builtin_amdgcn_sched_barrier(0);                     \
  } while (0)
#define LGKMC(n)                                           \
  do {                                                     \
    asm volatile("s_waitcnt lgkmcnt(" #n ")" ::: "memory");\
    __builtin_amdgcn_sched_barrier(0);                     \
  } while (0)
#define BAR()                                              \
  do {                                                     \
    asm volatile("" ::: "memory");                         \
    __builtin_amdgcn_s_barrier();                          \
    asm volatile("" ::: "memory");                         \
  } while (0)
#define RD64(dst, addr, imm) \
  asm volatile("ds_read_b64 %0, %1 offset:%c2" : "=v"(dst) : "v"(addr), "i"(imm))
#define RD4(P, base_)                 \
  do {                                \
    RD64(P##0, ringA, (base_));       \
    RD64(P##1, ringA, (base_) + 1024);\
    RD64(P##2, ringA, (base_) + 2048);\
    RD64(P##3, ringA, (base_) + 3072);\
  } while (0)
#define S4(P)                                     \
  do { stepv(P##0); stepv(P##1); stepv(P##2); stepv(P##3); } while (0)

// 16-group full-phase pipeline (3-buffer, steady lgkmcnt(8)); halo applied
// after the first counted wait.
#define PHASE_FULL()                                            \
  do {                                                          \
    u32x2 qA0, qA1, qA2, qA3, qB0, qB1, qB2, qB3,               \
          qC0, qC1, qC2, qC3;                                   \
    RD4(qA, 0); RD4(qB, 4096); RD4(qC, 8192);                   \
    LGKMC(8);                                                   \
    if (do_halo) {                                              \
      c0 = __uint_as_float(h01.x); c1 = __uint_as_float(h01.y); \
      c2 = __uint_as_float(h23.x); c3 = __uint_as_float(h23.y); \
    }                                                           \
    S4(qA); RD4(qA, 12288);                                     \
    LGKMC(8); S4(qB); RD4(qB, 16384);                           \
    LGKMC(8); S4(qC); RD4(qC, 20480);                           \
    LGKMC(8); S4(qA); RD4(qA, 24576);                           \
    LGKMC(8); S4(qB); RD4(qB, 28672);                           \
    LGKMC(8); S4(qC); RD4(qC, 32768);                           \
    LGKMC(8); S4(qA); RD4(qA, 36864);                           \
    LGKMC(8); S4(qB); RD4(qB, 40960);                           \
    LGKMC(8); S4(qC); RD4(qC, 45056);                           \
    LGKMC(8); S4(qA); RD4(qA, 49152);                           \
    LGKMC(8); S4(qB); RD4(qB, 53248);                           \
    LGKMC(8); S4(qC); RD4(qC, 57344);                           \
    LGKMC(8); S4(qA); RD4(qA, 61440);                           \
    LGKMC(8); S4(qB);                                           \
    LGKMC(4); S4(qC);                                           \
    LGKMC(0); S4(qA);                                           \
  } while (0)

__device__ __forceinline__ float dpp_shr1_neginf(float x) {  // dst[i]=src[i-1]
  int r = __builtin_amdgcn_update_dpp(__float_as_int(NEG_INF), __float_as_int(x),
                                      0x138, 0xf, 0xf, false);  // wave_shr:1
  return __int_as_float(r);
}
__device__ __forceinline__ float dpp_shl1_neginf(float x) {  // dst[i]=src[i+1]
  int r = __builtin_amdgcn_update_dpp(__float_as_int(NEG_INF), __float_as_int(x),
                                      0x130, 0xf, 0xf, false);  // wave_shl:1
  return __int_as_float(r);
}

// ---------------- fused fwd/bwd scan: 64 blocks (0-31 fwd, 32-63 bwd) ----------
__global__ __launch_bounds__(256, 1) void scan_fused(const u16* __restrict__ logpT,
                                                     const int* __restrict__ mel_len,
                                                     const int* __restrict__ text_len,
                                                     float* __restrict__ cwsF,
                                                     float* __restrict__ cwsB) {
  __shared__ u16 ring[2][SROWS][L];   // 128 KB
  __shared__ float smem[2][L];        // 4 KB halo exchange
  int tid = threadIdx.x;
  int wave = tid >> 6;
  int lane = tid & 63;
  bool bwdk = (blockIdx.x >= B);
  int b = bwdk ? (int)blockIdx.x - B : (int)blockIdx.x;
  int ml = get_len(mel_len, b);
  int tl = get_len(text_len, b);
  int tmid = ml >> 1;
  const u16* base0 = logpT + (size_t)b * T * L;

  if (!bwdk) {
    // ================= forward: alpha over t in [0, tmid) =================
    float* cws = cwsF + b * L;
    int col_lane = 128 * wave - 128 + 4 * lane;
    int cl = (col_lane < 0) ? 0 : col_lane;
    bool halo_lane = (wave > 0) && (lane < 32);
    bool owner = (lane >= 32);

    float c0 = NEG_INF, c1 = NEG_INF, c2 = NEG_INF, c3 = NEG_INF;
    if (wave == 0 && lane == 32) c0 = __uint_as_float((u32)base0[0] << 16);
    int tstart = 1;
    int tstop = tmid;
    int nrows = tstop - tstart;

    auto stepv = [&](u32x2 v) {
      float p = dpp_shr1_neginf(c3);
      float f0 = __uint_as_float(v.x << 16);
      float f1 = __uint_as_float(v.x & 0xFFFF0000u);
      float f2 = __uint_as_float(v.y << 16);
      float f3 = __uint_as_float(v.y & 0xFFFF0000u);
      c3 = fmaxf(c3, c2) + f3;
      c2 = fmaxf(c2, c1) + f2;
      c1 = fmaxf(c1, c0) + f1;
      c0 = fmaxf(c0, p) + f0;
    };

    if (nrows > 0) {
      int np = (nrows + SROWS - 1) / SROWS;
      int tlast = tstop - 1;
      auto stage = [&](int ph) -> bool {
        if (ph >= np) return false;
        int pr = tstart + ph * SROWS + 16 * wave;
        u16* d0 = &ring[ph & 1][16 * wave][0];
#pragma unroll
        for (int j = 0; j < 16; ++j) {
          int t = pr + j;
          t = (t > tlast) ? tlast : t;
          const u16* s = base0 + (size_t)t * L + lane * 8;
          __builtin_amdgcn_global_load_lds(
              (const __attribute__((address_space(1))) void*)s,
              (__attribute__((address_space(3))) void*)(d0 + (size_t)j * L + lane * 8),
              16, 0, 0);
        }
        return true;
      };
      stage(0);
      for (int k = 0; k < np; ++k) {
        BAR();
        u32x2 h01, h23;
        bool do_halo = (k > 0) && halo_lane;
        if (do_halo) {
          u32 ha = (u32)(uintptr_t)(__attribute__((address_space(3)))
                                    float*)(&smem[(k - 1) & 1][col_lane]);
          RD64(h01, ha, 0);
          RD64(h23, ha, 8);
        }
        bool nx = stage(k + 1);
        if (nx) VMW(16); else VMW(0);
        BAR();
        int rem = nrows - k * SROWS;
        if (rem > SROWS) rem = SROWS;
        u32 ringA = (u32)(uintptr_t)(__attribute__((address_space(3)))
                                     u16*)(&ring[k & 1][0][0]) +
                    2u * (u32)cl;
        if (rem == SROWS) {
          PHASE_FULL();
        } else {
          LGKMC(0);
          if (do_halo) {
            c0 = __uint_as_float(h01.x); c1 = __uint_as_float(h01.y);
            c2 = __uint_as_float(h23.x); c3 = __uint_as_float(h23.y);
          }
          const char* rp = (const char*)(&ring[k & 1][0][0]) + 2 * cl;
          for (int r = 0; r < rem; ++r) {
            u32x2 v = *(const u32x2*)(rp + (size_t)r * (L * 2));
            stepv(v);
          }
        }
        if (owner) *(float4*)&smem[k & 1][col_lane] = make_float4(c0, c1, c2, c3);
        LGKMC(0);
      }
    }
    if (owner) *(float4*)(cws + col_lane) = make_float4(c0, c1, c2, c3);
  } else {
    // ============ backward: beta over t in [tmid, ml), mirrored ============
    float* cws = cwsB + b * L;
    int col_lane = 128 * wave + 4 * lane;        // up to 639 for wave3 halo
    int cl = (col_lane > 508) ? 508 : col_lane;  // clamped for loads
    bool halo_lane = (lane >= 32) && (wave < 3);
    bool owner = (lane < 32);

    float c0 = NEG_INF, c1 = NEG_INF, c2 = NEG_INF, c3 = NEG_INF;
    {
      int li = tl - 1;
      int d = li - col_lane;
      if (d >= 0 && d < 4) {
        float v = __uint_as_float((u32)base0[(size_t)(ml - 1) * L + li] << 16);
        if (d == 0) c0 = v; else if (d == 1) c1 = v;
        else if (d == 2) c2 = v; else c3 = v;
      }
    }
    int nrows = ml - 1 - tmid;  // steps t = ml-2 .. tmid
    int tb0 = ml - 2;

    auto stepv = [&](u32x2 v) {  // backward step (right-neighbor via shl)
      float p = dpp_shl1_neginf(c0);
      float f0 = __uint_as_float(v.x << 16);
      float f1 = __uint_as_float(v.x & 0xFFFF0000u);
      float f2 = __uint_as_float(v.y << 16);
      float f3 = __uint_as_float(v.y & 0xFFFF0000u);
      c0 = fmaxf(c0, c1) + f0;
      c1 = fmaxf(c1, c2) + f1;
      c2 = fmaxf(c2, c3) + f2;
      c3 = fmaxf(c3, p) + f3;
    };

    if (nrows > 0) {
      int np = (nrows + SROWS - 1) / SROWS;
      auto stage = [&](int ph) -> bool {
        if (ph >= np) return false;
        int pr = tb0 - ph * SROWS - 16 * wave;
        u16* d0 = &ring[ph & 1][16 * wave][0];
#pragma unroll
        for (int j = 0; j < 16; ++j) {
          int t = pr - j;
          t = (t < 0) ? 0 : t;
          const u16* s = base0 + (size_t)t * L + lane * 8;
          __builtin_amdgcn_global_load_lds(
              (const __attribute__((address_space(1))) void*)s,
              (__attribute__((address_space(3))) void*)(d0 + (size_t)j * L + lane * 8),
              16, 0, 0);
        }
        return true;
      };
      stage(0);
      for (int k = 0; k < np; ++k) {
        BAR();
        u32x2 h01, h23;
        bool do_halo = (k > 0) && halo_lane;
        if (do_halo) {
          u32 ha = (u32)(uintptr_t)(__attribute__((address_space(3)))
                                    float*)(&smem[(k - 1) & 1][col_lane]);
          RD64(h01, ha, 0);
          RD64(h23, ha, 8);
        }
        bool nx = stage(k + 1);
        if (nx) VMW(16); else VMW(0);
        BAR();
        int rem = nrows - k * SROWS;
        if (rem > SROWS) rem = SROWS;
        u32 ringA = (u32)(uintptr_t)(__attribute__((address_space(3)))
                                     u16*)(&ring[k & 1][0][0]) +
                    2u * (u32)cl;
        if (rem == SROWS) {
          PHASE_FULL();
        } else {
          LGKMC(0);
          if (do_halo) {
            c0 = __uint_as_float(h01.x); c1 = __uint_as_float(h01.y);
            c2 = __uint_as_float(h23.x); c3 = __uint_as_float(h23.y);
          }
          const char* rp = (const char*)(&ring[k & 1][0][0]) + 2 * cl;
          for (int r = 0; r < rem; ++r) {
            u32x2 v = *(const u32x2*)(rp + (size_t)r * (L * 2));
            stepv(v);
          }
        }
        if (owner) *(float4*)&smem[k & 1][col_lane] = make_float4(c0, c1, c2, c3);
        LGKMC(0);
      }
    }
    if (owner) *(float4*)(cws + col_lane) = make_float4(c0, c1, c2, c3);
  }
}

// ---------------- combine: la[b] = max_l alpha[tmid-1][l] + max(beta[l],beta[l+1])
__global__ __launch_bounds__(64) void combine_kernel(const float* __restrict__ cwsF,
                                                     const float* __restrict__ cwsB,
                                                     float* __restrict__ la_ws) {
  int b = blockIdx.x;
  int lane = threadIdx.x;
  const float* f = cwsF + b * L;
  const float* bb = cwsB + b * L;
  float m = NEG_INF;
#pragma unroll
  for (int j = 0; j < 8; ++j) {
    int l = lane * 8 + j;
    float b0 = bb[l];
    float b1 = (l + 1 < L) ? bb[l + 1] : NEG_INF;
    m = fmaxf(m, f[l] + fmaxf(b0, b1));
  }
#pragma unroll
  for (int s = 32; s > 0; s >>= 1) m = fmaxf(m, __shfl_down(m, s));
  if (lane == 0) la_ws[b] = m;
}

// ---------------- fallback chunked forward scan (R19, proven) ----------------
__global__ __launch_bounds__(256, 1) void scan_kernel(const u16* __restrict__ logpT,
                                                      const int* __restrict__ mel_len,
                                                      const int* __restrict__ text_len,
                                                      float* __restrict__ carry_ws,
                                                      float* __restrict__ la_ws,
                                                      int t_begin, int tc) {
  __shared__ u16 ring[2][SROWS][L];
  __shared__ float smem[2][L];
  int tid = threadIdx.x;
  int wave = tid >> 6;
  int lane = tid & 63;
  int b = blockIdx.x;
  int ml = get_len(mel_len, b);
  int tl = get_len(text_len, b);
  const u16* base0 = logpT + (size_t)b * tc * L;
  float* cws = carry_ws + b * L;
  int col_lane = 128 * wave - 128 + 4 * lane;
  int cl = (col_lane < 0) ? 0 : col_lane;
  bool halo_lane = (wave > 0) && (lane < 32);
  bool owner = (lane >= 32);

  float c0 = NEG_INF, c1 = NEG_INF, c2 = NEG_INF, c3 = NEG_INF;
  int tstart;
  if (t_begin == 0) {
    if (wave == 0 && lane == 32) c0 = __uint_as_float((u32)base0[0] << 16);
    tstart = 1;
  } else {
    float4 v = *(const float4*)(cws + cl);
    c0 = v.x; c1 = v.y; c2 = v.z; c3 = v.w;
    if (col_lane < 0) { c0 = NEG_INF; c1 = NEG_INF; c2 = NEG_INF; c3 = NEG_INF; }
    tstart = t_begin;
  }

  int tstop = min(t_begin + tc, ml);
  int nrows = tstop - tstart;

  auto stepv = [&](u32x2 v) {
    float p = dpp_shr1_neginf(c3);
    float f0 = __uint_as_float(v.x << 16);
    float f1 = __uint_as_float(v.x & 0xFFFF0000u);
    float f2 = __uint_as_float(v.y << 16);
    float f3 = __uint_as_float(v.y & 0xFFFF0000u);
    c3 = fmaxf(c3, c2) + f3;
    c2 = fmaxf(c2, c1) + f2;
    c1 = fmaxf(c1, c0) + f1;
    c0 = fmaxf(c0, p) + f0;
  };

  if (nrows > 0) {
    int np = (nrows + SROWS - 1) / SROWS;
    int tlast = tstop - 1;
    auto stage = [&](int ph) -> bool {
      if (ph >= np) return false;
      int pr = tstart + ph * SROWS + 16 * wave;
      u16* d0 = &ring[ph & 1][16 * wave][0];
#pragma unroll
      for (int j = 0; j < 16; ++j) {
        int t = pr + j;
        t = (t > tlast) ? tlast : t;
        const u16* s = base0 + (size_t)(t - t_begin) * L + lane * 8;
        __builtin_amdgcn_global_load_lds(
            (const __attribute__((address_space(1))) void*)s,
            (__attribute__((address_space(3))) void*)(d0 + (size_t)j * L + lane * 8),
            16, 0, 0);
      }
      return true;
    };
    stage(0);
    for (int k = 0; k < np; ++k) {
      BAR();
      u32x2 h01, h23;
      bool do_halo = (k > 0) && halo_lane;
      if (do_halo) {
        u32 ha = (u32)(uintptr_t)(__attribute__((address_space(3)))
                                  float*)(&smem[(k - 1) & 1][col_lane]);
        RD64(h01, ha, 0);
        RD64(h23, ha, 8);
      }
      bool nx = stage(k + 1);
      if (nx) VMW(16); else VMW(0);
      BAR();
      int rem = nrows - k * SROWS;
      if (rem > SROWS) rem = SROWS;
      u32 ringA = (u32)(uintptr_t)(__attribute__((address_space(3)))
                                   u16*)(&ring[k & 1][0][0]) +
                  2u * (u32)cl;
      if (rem == SROWS) {
        PHASE_FULL();
      } else {
        LGKMC(0);
        if (do_halo) {
          c0 = __uint_as_float(h01.x); c1 = __uint_as_float(h01.y);
          c2 = __uint_as_float(h23.x); c3 = __uint_as_float(h23.y);
        }
        const char* rp = (const char*)(&ring[k & 1][0][0]) + 2 * cl;
        for (int r = 0; r < rem; ++r) {
          u32x2 v = *(const u32x2*)(rp + (size_t)r * (L * 2));
          stepv(v);
        }
      }
      if (owner) *(float4*)&smem[k & 1][col_lane] = make_float4(c0, c1, c2, c3);
      LGKMC(0);
    }
  }

  if (owner) *(float4*)(cws + col_lane) = make_float4(c0, c1, c2, c3);

  if (t_begin + tc >= T) {
    int li = tl - 1;
    int w_own = li >> 7;
    if (wave == w_own) {
      int sub = li & 3;
      float v = (sub == 0) ? c0 : (sub == 1) ? c1 : (sub == 2) ? c2 : c3;
      float lav = __shfl(v, 32 + ((li & 127) >> 2));
      if (lane == 0) la_ws[b] = lav;
    }
  }
}

__global__ __launch_bounds__(64) void reduce_kernel(const float* __restrict__ la_ws,
                                                    float* __restrict__ out) {
  int lane = threadIdx.x;
  float v = (lane < B) ? la_ws[lane] : 0.f;
#pragma unroll
  for (int s = 32; s > 0; s >>= 1) v += __shfl_down(v, s);
  if (lane == 0) out[0] = -v * (1.0f / (float)B);
}

extern "C" void kernel_launch(void* const* d_in, const int* in_sizes, int n_in,
                              void* d_out, int out_size, void* d_ws, size_t ws_size,
                              hipStream_t stream) {
  const float* mu_sigma = (const float*)d_in[0];
  const float* melspec  = (const float*)d_in[1];
  const int*   text_len = (const int*)d_in[2];
  const int*   mel_len  = (const int*)d_in[3];
  float* out = (float*)d_out;

  char* ws = (char*)d_ws;
  size_t off = 0;
  u16* Wfrag = (u16*)(ws + off);         off += (size_t)B * KDIM * L * 2;      // 5.2 MB
  float* biasv = (float*)(ws + off);     off += (size_t)B * L * 4;
  float* cwsF = (float*)(ws + off);      off += (size_t)B * L * 4;
  float* cwsB = (float*)(ws + off);      off += (size_t)B * L * 4;
  float* la_ws = (float*)(ws + off);     off += 256;
  u16* Xfrag = (u16*)(ws + off);         off += (size_t)B * KDIM * T * 2;      // 21 MB
  u16* logpT = (u16*)(ws + off);
  size_t avail = (ws_size > off) ? (ws_size - off) : 0;
  size_t per_t = (size_t)B * L * 2;  // bytes per t-slice across all b (bf16)
  long long tcl = (long long)(avail / per_t);
  int Tc = (tcl > T) ? T : (int)tcl;
  Tc &= ~63;
  if (Tc < 64) return;  // insufficient workspace (not expected)

  prep_kernel<<<dim3((B * L + 255) / 256), 256, 0, stream>>>(mu_sigma, Wfrag, biasv);
  xprep_kernel<<<dim3((B * 10 * T) / 256), 256, 0, stream>>>(melspec, Xfrag);

  if (Tc == T) {
    // primary: single-chunk, fused fwd/bwd scan on 64 CUs
    dim3 grid(T / 64, L / 128, B);
    gemm_logp<<<grid, 256, 0, stream>>>(Xfrag, Wfrag, biasv, mel_len, text_len,
                                        logpT, 0, T);
    scan_fused<<<dim3(2 * B), 256, 0, stream>>>(logpT, mel_len, text_len, cwsF, cwsB);
    combine_kernel<<<dim3(B), 64, 0, stream>>>(cwsF, cwsB, la_ws);
  } else {
    // fallback: chunked forward-only (R19 path)
    for (int t_begin = 0; t_begin < T; t_begin += Tc) {
      int tc = (T - t_begin < Tc) ? (T - t_begin) : Tc;
      dim3 grid(tc / 64, L / 128, B);
      gemm_logp<<<grid, 256, 0, stream>>>(Xfrag, Wfrag, biasv, mel_len, text_len,
                                          logpT, t_begin, tc);
      scan_kernel<<<dim3(B), 256, 0, stream>>>(logpT, mel_len, text_len, cwsF,
                                               la_ws, t_begin, tc);
    }
  }
  reduce_kernel<<<1, 64, 0, stream>>>(la_ws, out);
}